// Round 5
// baseline (181.238 us; speedup 1.0000x reference)
//
#include <hip/hip_runtime.h>
#include <cstdint>
#include <cstddef>

#define S_LEN 2047
#define BATCH 8
#define R_TOT 1162
#define NEGV (-1e9f)

// ws layout: state = 8*2047*6*4 = 393,024 B at offset 0 (round-1-proven),
//            params = 16376 rows * 20 ints * 4 B = 1,310,080 B at offset 393,024.
#define PARAM_OFF 393024
#define PSTRIDE 20

__device__ __constant__ int d_numerators[12] = {1, 2, 3, 4, 5, 6, 7, 8, 9, 10, 12, 16};

// ---------------------------------------------------------------------------
// Kernel 1: per-batch prefix scan — VERBATIM from the round-1 PASSING kernel.
// State per position j (inclusive prefix over tokens 0..j):
//   word0: last_ks(0:8) | last_ts(8:16) | last_tp(16:24) | has_ks(24) | has_ts(25)
//   word1..5: 160-bit instrument-present bitmask (129 used)
// Value fields are pre-defaulted to song[b,0,{8,9,10}] (tf argmax-of-zeros).
// ---------------------------------------------------------------------------
__global__ __launch_bounds__(256) void scan_kernel(const int* __restrict__ song,
                                                   unsigned* __restrict__ state) {
    const int b = blockIdx.x;
    const int tid = threadIdx.x;
    __shared__ unsigned lds_f[3][256];
    __shared__ unsigned lds_inst[5][256];
    __shared__ unsigned bc[8];
    const unsigned HAS = 1u << 16;
    const long base = (long)b * S_LEN;

    unsigned c_f[3];
    unsigned c_inst[5] = {0, 0, 0, 0, 0};
    {
        const int* r0 = song + base * 11;
        c_f[0] = (unsigned)r0[8];
        c_f[1] = (unsigned)r0[9];
        c_f[2] = (unsigned)r0[10];
    }

    for (int chunk = 0; chunk < S_LEN; chunk += 256) {
        const int j = chunk + tid;
        unsigned e_f[3] = {0, 0, 0};
        unsigned e_inst[5] = {0, 0, 0, 0, 0};
        if (j < S_LEN) {
            const int* rj = song + (base + j) * 11;
            const int type = rj[0];
            if (type == 4)      e_f[0] = HAS | (unsigned)rj[8];
            else if (type == 5) e_f[1] = HAS | (unsigned)rj[9];
            else if (type == 6) e_f[2] = HAS | (unsigned)rj[10];
            else if (type == 1) { const int v = rj[6]; e_inst[v >> 5] = 1u << (v & 31); }
        }
#pragma unroll
        for (int w = 0; w < 3; w++) lds_f[w][tid] = e_f[w];
#pragma unroll
        for (int w = 0; w < 5; w++) lds_inst[w][tid] = e_inst[w];
        __syncthreads();

        for (int off = 1; off < 256; off <<= 1) {
            unsigned p_f[3] = {0, 0, 0};
            unsigned p_inst[5] = {0, 0, 0, 0, 0};
            if (tid >= off) {
#pragma unroll
                for (int w = 0; w < 3; w++) p_f[w] = lds_f[w][tid - off];
#pragma unroll
                for (int w = 0; w < 5; w++) p_inst[w] = lds_inst[w][tid - off];
            }
            __syncthreads();
            if (tid >= off) {
#pragma unroll
                for (int w = 0; w < 3; w++) {
                    if (!(e_f[w] & HAS)) e_f[w] = p_f[w];
                    lds_f[w][tid] = e_f[w];
                }
#pragma unroll
                for (int w = 0; w < 5; w++) {
                    e_inst[w] |= p_inst[w];
                    lds_inst[w][tid] = e_inst[w];
                }
            }
            __syncthreads();
        }

        unsigned t_f[3], t_inst[5];
#pragma unroll
        for (int w = 0; w < 3; w++) t_f[w] = (e_f[w] & HAS) ? e_f[w] : c_f[w];
#pragma unroll
        for (int w = 0; w < 5; w++) t_inst[w] = e_inst[w] | c_inst[w];

        if (j < S_LEN) {
            const unsigned pack =
                (t_f[0] & 0xFFu) | ((t_f[1] & 0xFFu) << 8) | ((t_f[2] & 0xFFu) << 16) |
                (((t_f[0] >> 16) & 1u) << 24) | (((t_f[1] >> 16) & 1u) << 25);
            unsigned* sp = state + (size_t)(base + j) * 6;
            sp[0] = pack;
#pragma unroll
            for (int w = 0; w < 5; w++) sp[1 + w] = t_inst[w];
        }

        const int last = min(255, S_LEN - 1 - chunk);
        if (tid == last) {
#pragma unroll
            for (int w = 0; w < 3; w++) bc[w] = t_f[w];
#pragma unroll
            for (int w = 0; w < 5; w++) bc[3 + w] = t_inst[w];
        }
        __syncthreads();
#pragma unroll
        for (int w = 0; w < 3; w++) c_f[w] = bc[w];
#pragma unroll
        for (int w = 0; w < 5; w++) c_inst[w] = bc[3 + w];
        __syncthreads();
    }
}

// ---------------------------------------------------------------------------
// Kernel 2: per-row parameter computation — round-1 mask kernel's HEAD
// verbatim (LDS slots, 128-slot tree argmax, thread-0 beat scan + scalar
// epilogue). Writes the 17 per-row mask params to ws instead of applying.
// ---------------------------------------------------------------------------
__global__ __launch_bounds__(256) void param_kernel(const int* __restrict__ song,
                                                    const int* __restrict__ ctype,
                                                    const float* __restrict__ scores,
                                                    const unsigned* __restrict__ state,
                                                    int* __restrict__ params) {
    const int row = blockIdx.x;
    const int tid = threadIdx.x;
    const int b = row / S_LEN;
    const int i = row - b * S_LEN;

    __shared__ float s_val[128];
    __shared__ int   s_idx[128];
    __shared__ float sb_val[8];
    __shared__ int   sb_idx[8];
    __shared__ int   s_info[10];

    const size_t rbase = (size_t)row * R_TOT;
    const float2* s2 = (const float2*)(scores + rbase);

    const float2 r0 = s2[tid];  // tid<136 used; rest harmless (581 float2/row)

    if (tid < 128) {
        const bool sec = (r0.y > r0.x);
        s_val[tid] = sec ? r0.y : r0.x;
        s_idx[tid] = 2 * tid + (sec ? 1 : 0);
    } else if (tid < 136) {
        const bool sec = (r0.y > r0.x);
        sb_val[tid - 128] = sec ? r0.y : r0.x;
        sb_idx[tid - 128] = (2 * tid - 256) + (sec ? 1 : 0);
    } else if (tid < 142) {
        const int e = min(i + 1, S_LEN - 1);
        s_info[tid - 136] = (int)state[((size_t)b * S_LEN + e) * 6 + (tid - 136)];
    } else if (tid < 146) {
        const int* srow = song + (size_t)row * 11;
        if (tid == 142) s_info[6] = srow[1];
        if (tid == 143) s_info[7] = srow[2];
        if (tid == 144) s_info[8] = srow[3];
        if (tid == 145) s_info[9] = ctype[row];
    }
    __syncthreads();

    for (int s = 64; s > 0; s >>= 1) {
        if (tid < s) {
            if (s_val[tid + s] > s_val[tid]) {  // strict > keeps lower index on tie
                s_val[tid] = s_val[tid + s];
                s_idx[tid] = s_idx[tid + s];
            }
        }
        __syncthreads();
    }

    if (tid == 0) {
        const int pred_m = s_idx[0];
        float bv = sb_val[0];
        int pred_b = sb_idx[0];
#pragma unroll
        for (int q = 1; q < 8; q++) {
            if (sb_val[q] > bv) { bv = sb_val[q]; pred_b = sb_idx[q]; }
        }
        const unsigned pack = (unsigned)s_info[0];
        const int song1 = s_info[6], song2 = s_info[7], song3 = s_info[8];
        const int t = s_info[9];
        const bool c1 = (pred_m == song1);
        const int min_beat = c1 ? song2 : 0;
        const bool c2 = c1 && (pred_b == min_beat);
        const int min_pos = c2 ? song3 : 0;
        const int last_ks = (int)(pack & 0xFFu);
        const int last_ts = (int)((pack >> 8) & 0xFFu);
        const int last_tp = (int)((pack >> 16) & 0xFFu);
        const unsigned u = (unsigned)s_info[1] | (unsigned)s_info[2] | (unsigned)s_info[3] |
                           (unsigned)s_info[4] | (unsigned)s_info[5];
        int* pp = params + (size_t)row * PSTRIDE;
        pp[0] = t;
        pp[1] = song1;                                            // min_measure
        pp[2] = min_beat;
        pp[3] = min_pos;
        pp[4] = (song2 == 0 && song3 == 0) ? song1 : song1 + 1;   // min_m46
        pp[5] = d_numerators[last_ts % 12];                       // max_beat
        pp[6] = last_ks;
        pp[7] = last_ts;
        pp[8] = last_tp;
        pp[9]  = (int)((pack >> 24) & 1u);                        // has_ks
        pp[10] = (int)((pack >> 25) & 1u);                        // has_ts
        pp[11] = (u != 0u);                                       // has_inst
        pp[12] = s_info[1]; pp[13] = s_info[2]; pp[14] = s_info[3];
        pp[15] = s_info[4]; pp[16] = s_info[5];
    }
}

// ---------------------------------------------------------------------------
// Kernel 3: mask application — round-1 mask kernel's EPILOGUE verbatim
// (maskf branch form + 3x strided float2 stores). No LDS, no barriers;
// params are block-uniform scalar loads.
// ---------------------------------------------------------------------------
__global__ __launch_bounds__(256) void apply_kernel(const float* __restrict__ scores,
                                                    const int* __restrict__ params,
                                                    float* __restrict__ out) {
    const int row = blockIdx.x;
    const int tid = threadIdx.x;

    const size_t rbase = (size_t)row * R_TOT;
    const float2* s2 = (const float2*)(scores + rbase);
    float2* o2 = (float2*)(out + rbase);

    const float2 r0 = s2[tid];
    const float2 r1 = s2[tid + 256];
    float2 r2 = make_float2(0.f, 0.f);
    if (tid < 69) r2 = s2[tid + 512];

    const int* pp = params + (size_t)row * PSTRIDE;  // block-uniform
    const int t = pp[0];
    const int min_measure = pp[1], min_beat = pp[2], min_pos = pp[3];
    const int min_m46 = pp[4], max_beat = pp[5];
    const int last_ks = pp[6], last_ts = pp[7], last_tp = pp[8];
    const bool has_ks = pp[9] != 0, has_ts = pp[10] != 0, has_inst = pp[11] != 0;
    unsigned inst[5];
#pragma unroll
    for (int w = 0; w < 5; w++) inst[w] = (unsigned)pp[12 + w];
    const bool is3 = (t == 3);
    const bool is46 = (t >= 4) && (t <= 6);

    // Range offsets: measure 0..256, beat 256..272, position 272..400,
    // duration 400..528, pitch 528..784, instrument 784..913,
    // velocity 913..1041, key_sign 1041..1065, time_sign 1065..1113,
    // tempo 1113..1162
    auto maskf = [&](int col) -> bool {
        if (col < 256) {
            if (is3) return col >= min_measure;
            if (is46) return col >= min_m46;
            return true;
        } else if (col < 272) {
            if (!is3) return true;
            const int v = col - 256;
            return (v >= min_beat) && (v < max_beat);
        } else if (col < 400) {
            return is3 ? ((col - 272) >= min_pos) : true;
        } else if (col < 784) {
            return true;  // duration + pitch
        } else if (col < 913) {
            const int v = col - 784;
            const bool pres = ((inst[v >> 5] >> (v & 31)) & 1u) != 0u;
            if (is3) return pres;
            if (t == 1) return has_inst ? !pres : true;
            return true;
        } else if (col < 1041) {
            return true;  // velocity
        } else if (col < 1065) {
            const int v = col - 1041;
            if (is3) return v == last_ks;
            if (t == 4) return has_ks ? (v != last_ks) : true;
            return true;
        } else if (col < 1113) {
            const int v = col - 1065;
            if (is3) return v == last_ts;
            if (t == 5) return has_ts ? (v != last_ts) : true;
            return true;
        } else {
            const int v = col - 1113;
            if (is3) return v == last_tp;
            if (t == 6) return v != last_tp;  // no has-check for tempo
            return true;
        }
    };

    float2 w;
    int c = 2 * tid;
    w.x = maskf(c)     ? r0.x : NEGV;
    w.y = maskf(c + 1) ? r0.y : NEGV;
    o2[tid] = w;

    c = 512 + 2 * tid;
    w.x = maskf(c)     ? r1.x : NEGV;
    w.y = maskf(c + 1) ? r1.y : NEGV;
    o2[tid + 256] = w;

    if (tid < 69) {
        c = 1024 + 2 * tid;
        w.x = maskf(c)     ? r2.x : NEGV;
        w.y = maskf(c + 1) ? r2.y : NEGV;
        o2[tid + 512] = w;
    }
}

extern "C" void kernel_launch(void* const* d_in, const int* in_sizes, int n_in,
                              void* d_out, int out_size, void* d_ws, size_t ws_size,
                              hipStream_t stream) {
    const int* song = (const int*)d_in[0];
    const int* ctype = (const int*)d_in[1];
    const float* scores = (const float*)d_in[2];
    float* out = (float*)d_out;
    unsigned* state = (unsigned*)d_ws;                    // offset 0, 393,024 B
    int* params = (int*)((char*)d_ws + PARAM_OFF);        // 16376*20*4 = 1,310,080 B

    scan_kernel<<<BATCH, 256, 0, stream>>>(song, state);
    param_kernel<<<BATCH * S_LEN, 256, 0, stream>>>(song, ctype, scores, state, params);
    apply_kernel<<<BATCH * S_LEN, 256, 0, stream>>>(scores, params, out);
}

// Round 6
// 154.205 us; speedup vs baseline: 1.1753x; 1.1753x over previous
//
#include <hip/hip_runtime.h>
#include <cstdint>
#include <cstddef>

#define S_LEN 2047
#define BATCH 8
#define R_TOT 1162
#define NCHUNK 8
#define NEGV (-1e9f)

// ws layout: local = 8*2047*6*4 = 393,024 B at offset 0,
//            carry = 8*8*6*4 = 1,536 B at offset 393,024.
#define CARRY_OFF 393024

__device__ __constant__ int d_numerators[12] = {1, 2, 3, 4, 5, 6, 7, 8, 9, 10, 12, 16};

// ---------------------------------------------------------------------------
// Kernel 1: within-chunk inclusive scan (64 blocks = 8 batches x 8 chunks).
// Chunk-local state per position j:
//   word0: ks(0:8) | ts(8:16) | tp(16:24) | has_ks(24) | has_ts(25) | has_tp(26)
//   word1..5: 160-bit instrument-present bitmask
// During the scan per-field words are (has<<16)|val so combine = select.
// ---------------------------------------------------------------------------
__global__ __launch_bounds__(256) void scan_local(const int* __restrict__ song,
                                                  unsigned* __restrict__ local) {
    const int b = blockIdx.x >> 3;
    const int c = blockIdx.x & 7;
    const int tid = threadIdx.x;
    const int j = c * 256 + tid;
    __shared__ unsigned lds_f[3][256];
    __shared__ unsigned lds_inst[5][256];
    const unsigned HAS = 1u << 16;
    const long base = (long)b * S_LEN;

    unsigned e_f[3] = {0, 0, 0};
    unsigned e_inst[5] = {0, 0, 0, 0, 0};
    if (j < S_LEN) {
        const int* rj = song + (base + j) * 11;
        const int type = rj[0];
        if (type == 4)      e_f[0] = HAS | (unsigned)rj[8];
        else if (type == 5) e_f[1] = HAS | (unsigned)rj[9];
        else if (type == 6) e_f[2] = HAS | (unsigned)rj[10];
        else if (type == 1) { const int v = rj[6]; e_inst[v >> 5] = 1u << (v & 31); }
    }
#pragma unroll
    for (int w = 0; w < 3; w++) lds_f[w][tid] = e_f[w];
#pragma unroll
    for (int w = 0; w < 5; w++) lds_inst[w][tid] = e_inst[w];
    __syncthreads();

    for (int off = 1; off < 256; off <<= 1) {
        unsigned p_f[3] = {0, 0, 0};
        unsigned p_inst[5] = {0, 0, 0, 0, 0};
        if (tid >= off) {
#pragma unroll
            for (int w = 0; w < 3; w++) p_f[w] = lds_f[w][tid - off];
#pragma unroll
            for (int w = 0; w < 5; w++) p_inst[w] = lds_inst[w][tid - off];
        }
        __syncthreads();
        if (tid >= off) {
#pragma unroll
            for (int w = 0; w < 3; w++) {
                if (!(e_f[w] & HAS)) e_f[w] = p_f[w];
                lds_f[w][tid] = e_f[w];
            }
#pragma unroll
            for (int w = 0; w < 5; w++) {
                e_inst[w] |= p_inst[w];
                lds_inst[w][tid] = e_inst[w];
            }
        }
        __syncthreads();
    }

    if (j < S_LEN) {
        const unsigned w0 =
            (e_f[0] & 0xFFu) | ((e_f[1] & 0xFFu) << 8) | ((e_f[2] & 0xFFu) << 16) |
            (((e_f[0] >> 16) & 1u) << 24) | (((e_f[1] >> 16) & 1u) << 25) |
            (((e_f[2] >> 16) & 1u) << 26);
        unsigned* sp = local + (size_t)(base + j) * 6;
        sp[0] = w0;
#pragma unroll
        for (int w = 0; w < 5; w++) sp[1 + w] = e_inst[w];
    }
}

// ---------------------------------------------------------------------------
// Kernel 2: exclusive per-chunk carries. 1 tiny block; lane b folds the 8
// chunk aggregates (= chunk-local state at each chunk's last position).
// Carry value fields pre-defaulted to song[b,0,{8,9,10}] (tf argmax-of-zeros
// default), has-bits in carry word0 bits 24/25/26.
// ---------------------------------------------------------------------------
__global__ __launch_bounds__(64) void scan_carry(const int* __restrict__ song,
                                                 const unsigned* __restrict__ local,
                                                 unsigned* __restrict__ carry) {
    const int b = threadIdx.x;
    if (b >= BATCH) return;
    const int* r0 = song + (size_t)b * S_LEN * 11;
    unsigned cks = (unsigned)r0[8], cts = (unsigned)r0[9], ctp = (unsigned)r0[10];
    unsigned chas = 0;  // bit0 has_ks, bit1 has_ts, bit2 has_tp
    unsigned cinst[5] = {0, 0, 0, 0, 0};
    for (int c = 0; c < NCHUNK; c++) {
        unsigned* cp = carry + ((size_t)b * NCHUNK + c) * 6;
        cp[0] = (cks & 0xFFu) | ((cts & 0xFFu) << 8) | ((ctp & 0xFFu) << 16) | (chas << 24);
#pragma unroll
        for (int w = 0; w < 5; w++) cp[1 + w] = cinst[w];
        const int pos = min((c + 1) * 256, S_LEN) - 1;
        const unsigned* lp = local + ((size_t)b * S_LEN + pos) * 6;
        const unsigned a0 = lp[0];
        if ((a0 >> 24) & 1u) cks = a0 & 0xFFu;
        if ((a0 >> 25) & 1u) cts = (a0 >> 8) & 0xFFu;
        if ((a0 >> 26) & 1u) ctp = (a0 >> 16) & 0xFFu;
        chas |= (a0 >> 24) & 7u;
#pragma unroll
        for (int w = 0; w < 5; w++) cinst[w] |= lp[1 + w];
    }
}

// ---------------------------------------------------------------------------
// Kernel 3: monolithic mask kernel — VERBATIM the round-1 PASSING kernel,
// except the 6-thread state-load branch now combines (local word, carry word)
// into the round-1 s_info format: word0 = per-field has-select + repack
// (has_ks bit24, has_ts bit25), words 1..5 = OR. Everything downstream of
// s_info[] is byte-identical to round 1.
// ---------------------------------------------------------------------------
__global__ __launch_bounds__(256) void mask_kernel(const int* __restrict__ song,
                                                   const int* __restrict__ ctype,
                                                   const float* __restrict__ scores,
                                                   const unsigned* __restrict__ local,
                                                   const unsigned* __restrict__ carry,
                                                   float* __restrict__ out) {
    const int row = blockIdx.x;
    const int tid = threadIdx.x;
    const int b = row / S_LEN;
    const int i = row - b * S_LEN;

    __shared__ float s_val[128];
    __shared__ int   s_idx[128];
    __shared__ float sb_val[8];
    __shared__ int   sb_idx[8];
    __shared__ int   s_info[10];
    __shared__ int   f_info[17];

    const size_t rbase = (size_t)row * R_TOT;
    const float2* s2 = (const float2*)(scores + rbase);
    float2* o2 = (float2*)(out + rbase);

    const float2 r0 = s2[tid];
    const float2 r1 = s2[tid + 256];
    float2 r2 = make_float2(0.f, 0.f);
    if (tid < 69) r2 = s2[tid + 512];

    if (tid < 128) {
        // measure candidates: cols 2*tid, 2*tid+1 (first index wins ties)
        const bool sec = (r0.y > r0.x);
        s_val[tid] = sec ? r0.y : r0.x;
        s_idx[tid] = 2 * tid + (sec ? 1 : 0);
    } else if (tid < 136) {
        // beat candidates: beat-relative cols 2*(tid-128), +1
        const bool sec = (r0.y > r0.x);
        sb_val[tid - 128] = sec ? r0.y : r0.x;
        sb_idx[tid - 128] = (2 * tid - 256) + (sec ? 1 : 0);
    } else if (tid < 142) {
        const int w = tid - 136;
        const int e = min(i + 1, S_LEN - 1);
        const unsigned lw = local[((size_t)b * S_LEN + e) * 6 + w];
        const unsigned cw = carry[((size_t)b * NCHUNK + (e >> 8)) * 6 + w];
        unsigned v;
        if (w == 0) {
            const unsigned ks = ((lw >> 24) & 1u) ? (lw & 0xFFu) : (cw & 0xFFu);
            const unsigned ts = ((lw >> 25) & 1u) ? ((lw >> 8) & 0xFFu) : ((cw >> 8) & 0xFFu);
            const unsigned tp = ((lw >> 26) & 1u) ? ((lw >> 16) & 0xFFu) : ((cw >> 16) & 0xFFu);
            const unsigned hks = ((lw >> 24) | (cw >> 24)) & 1u;
            const unsigned hts = ((lw >> 25) | (cw >> 25)) & 1u;
            v = ks | (ts << 8) | (tp << 16) | (hks << 24) | (hts << 25);
        } else {
            v = lw | cw;
        }
        s_info[w] = (int)v;
    } else if (tid < 146) {
        const int* srow = song + (size_t)row * 11;
        if (tid == 142) s_info[6] = srow[1];
        if (tid == 143) s_info[7] = srow[2];
        if (tid == 144) s_info[8] = srow[3];
        if (tid == 145) s_info[9] = ctype[row];
    }
    __syncthreads();

    for (int s = 64; s > 0; s >>= 1) {
        if (tid < s) {
            if (s_val[tid + s] > s_val[tid]) {  // strict > keeps lower index on tie
                s_val[tid] = s_val[tid + s];
                s_idx[tid] = s_idx[tid + s];
            }
        }
        __syncthreads();
    }

    if (tid == 0) {
        const int pred_m = s_idx[0];
        float bv = sb_val[0];
        int pred_b = sb_idx[0];
#pragma unroll
        for (int q = 1; q < 8; q++) {
            if (sb_val[q] > bv) { bv = sb_val[q]; pred_b = sb_idx[q]; }
        }
        const unsigned pack = (unsigned)s_info[0];
        const int song1 = s_info[6], song2 = s_info[7], song3 = s_info[8];
        const int t = s_info[9];
        const bool c1 = (pred_m == song1);
        const int min_beat = c1 ? song2 : 0;
        const bool c2 = c1 && (pred_b == min_beat);
        const int min_pos = c2 ? song3 : 0;
        const int last_ks = pack & 0xFF;
        const int last_ts = (pack >> 8) & 0xFF;
        const int last_tp = (pack >> 16) & 0xFF;
        f_info[0] = t;
        f_info[1] = song1;       // min_measure
        f_info[2] = min_beat;
        f_info[3] = min_pos;
        f_info[4] = (song2 == 0 && song3 == 0) ? song1 : song1 + 1;  // min_m46
        f_info[5] = d_numerators[last_ts % 12];                      // max_beat
        f_info[6] = last_ks;
        f_info[7] = last_ts;
        f_info[8] = last_tp;
        f_info[9]  = (int)((pack >> 24) & 1u);  // has_ks
        f_info[10] = (int)((pack >> 25) & 1u);  // has_ts
        const unsigned u = (unsigned)s_info[1] | (unsigned)s_info[2] | (unsigned)s_info[3] |
                           (unsigned)s_info[4] | (unsigned)s_info[5];
        f_info[11] = (u != 0u);                 // has_inst
        f_info[12] = s_info[1]; f_info[13] = s_info[2]; f_info[14] = s_info[3];
        f_info[15] = s_info[4]; f_info[16] = s_info[5];
    }
    __syncthreads();

    const int t = f_info[0];
    const int min_measure = f_info[1], min_beat = f_info[2], min_pos = f_info[3];
    const int min_m46 = f_info[4], max_beat = f_info[5];
    const int last_ks = f_info[6], last_ts = f_info[7], last_tp = f_info[8];
    const bool has_ks = f_info[9] != 0, has_ts = f_info[10] != 0, has_inst = f_info[11] != 0;
    unsigned inst[5];
#pragma unroll
    for (int w = 0; w < 5; w++) inst[w] = (unsigned)f_info[12 + w];
    const bool is3 = (t == 3);
    const bool is46 = (t >= 4) && (t <= 6);

    // Range offsets: measure 0..256, beat 256..272, position 272..400,
    // duration 400..528, pitch 528..784, instrument 784..913,
    // velocity 913..1041, key_sign 1041..1065, time_sign 1065..1113,
    // tempo 1113..1162
    auto maskf = [&](int col) -> bool {
        if (col < 256) {
            if (is3) return col >= min_measure;
            if (is46) return col >= min_m46;
            return true;
        } else if (col < 272) {
            if (!is3) return true;
            const int v = col - 256;
            return (v >= min_beat) && (v < max_beat);
        } else if (col < 400) {
            return is3 ? ((col - 272) >= min_pos) : true;
        } else if (col < 784) {
            return true;  // duration + pitch
        } else if (col < 913) {
            const int v = col - 784;
            const bool pres = ((inst[v >> 5] >> (v & 31)) & 1u) != 0u;
            if (is3) return pres;
            if (t == 1) return has_inst ? !pres : true;
            return true;
        } else if (col < 1041) {
            return true;  // velocity
        } else if (col < 1065) {
            const int v = col - 1041;
            if (is3) return v == last_ks;
            if (t == 4) return has_ks ? (v != last_ks) : true;
            return true;
        } else if (col < 1113) {
            const int v = col - 1065;
            if (is3) return v == last_ts;
            if (t == 5) return has_ts ? (v != last_ts) : true;
            return true;
        } else {
            const int v = col - 1113;
            if (is3) return v == last_tp;
            if (t == 6) return v != last_tp;  // no has-check for tempo
            return true;
        }
    };

    float2 w;
    int c = 2 * tid;
    w.x = maskf(c)     ? r0.x : NEGV;
    w.y = maskf(c + 1) ? r0.y : NEGV;
    o2[tid] = w;

    c = 512 + 2 * tid;
    w.x = maskf(c)     ? r1.x : NEGV;
    w.y = maskf(c + 1) ? r1.y : NEGV;
    o2[tid + 256] = w;

    if (tid < 69) {
        c = 1024 + 2 * tid;
        w.x = maskf(c)     ? r2.x : NEGV;
        w.y = maskf(c + 1) ? r2.y : NEGV;
        o2[tid + 512] = w;
    }
}

extern "C" void kernel_launch(void* const* d_in, const int* in_sizes, int n_in,
                              void* d_out, int out_size, void* d_ws, size_t ws_size,
                              hipStream_t stream) {
    const int* song = (const int*)d_in[0];
    const int* ctype = (const int*)d_in[1];
    const float* scores = (const float*)d_in[2];
    float* out = (float*)d_out;
    unsigned* local = (unsigned*)d_ws;                          // 393,024 B
    unsigned* carry = (unsigned*)((char*)d_ws + CARRY_OFF);     // 1,536 B

    scan_local<<<BATCH * NCHUNK, 256, 0, stream>>>(song, local);
    scan_carry<<<1, 64, 0, stream>>>(song, local, carry);
    mask_kernel<<<BATCH * S_LEN, 256, 0, stream>>>(song, ctype, scores, local, carry, out);
}